// Round 13
// baseline (99.112 us; speedup 1.0000x reference)
//
#include <hip/hip_runtime.h>
#include <math.h>

// Problem constants
constexpr int kB = 2;
constexpr int kC = 128;
constexpr int kN = 784;
constexpr float kInvT = 1.0f / 11.313708498984761f;  // 1/sqrt(C)
constexpr float kInvC = 1.0f / 128.0f;

constexpr size_t kOutElems  = (size_t)kB * kC * kN;  // 200704
constexpr size_t kAttnElems = (size_t)kB * kN * kN;  // 1229312

// dist_exp tiling: 32k x 64q, FULL c=128 (53.2 KB LDS), 128 threads, 4k x 4q/thread.
constexpr int DK = 32, DQ = 64;
constexpr int DNKT = 25, DNQT = 13;          // 25*32=800, 13*64=832 cover 784
constexpr int NDISTE = kB * DNKT * DNQT;     // 650 blocks
constexpr int KSTR = 36, QSTR = 68;          // padded rows (16B-mult, %32==4)

// bmm tiling: 64c x 64k, qsplit 14 (56 q each, 2 chunks of 28); one tile per block.
constexpr int BKT = 64, NKT2 = 13;
constexpr int QSP = 14, QPB = 56, QCH = 28;
constexpr int BSTR = 68;
constexpr int NBMM = kB * 2 * NKT2 * QSP;  // 728

constexpr int NROWS = kB * kN;      // 1568 attn rows
constexpr int NNORM = NROWS / 4;    // 392 normalize blocks (4 rows each)
constexpr int NOUTB = (int)(kOutElems / 4 / 256);  // 196 out-reduce blocks

__device__ inline float wave_max(float v) {
#pragma unroll
    for (int o = 32; o > 0; o >>= 1) v = fmaxf(v, __shfl_xor(v, o, 64));
    return v;
}
__device__ inline float wave_sum(float v) {
#pragma unroll
    for (int o = 32; o > 0; o >>= 1) v += __shfl_xor(v, o, 64);
    return v;
}

// ========== Kernel 1: p[b,k,q] = exp( sum_c |q/T - k| / 128 ), lp = per-tile row sums ==========
// Full c in LDS -> exp can be applied in-register (max-subtraction provably unneeded:
// exp arg = mean|.| in [~0.3, ~2]). Row-sum partials per (b,kt,qt) tile go to lp
// (no atomics); finalize sums the 13 qt entries.
__global__ __launch_bounds__(128) void dist_exp(const float* __restrict__ qg,
                                                const float* __restrict__ kg,
                                                float* __restrict__ attn,
                                                float* __restrict__ lp) {
    int bid = blockIdx.x;
    const int qt = bid % DNQT; bid /= DNQT;
    const int kt = bid % DNKT; bid /= DNKT;
    const int b  = bid;
    const int k0 = kt * DK;
    const int q0 = qt * DQ;
    const int t  = threadIdx.x;  // 0..127

    __shared__ float ks[kC][KSTR];  // 18.4 KB
    __shared__ float qs[kC][QSTR];  // 34.8 KB

    const float* kb = kg + (size_t)b * kC * kN;
    const float* qb = qg + (size_t)b * kC * kN;

    // Stage k-tile: 128 c x 8 float4 (8 iters of 128 threads).
#pragma unroll
    for (int i = t; i < kC * 8; i += 128) {
        const int c  = i >> 3;
        const int x4 = (i & 7) << 2;
        *reinterpret_cast<float4*>(&ks[c][x4]) =
            *reinterpret_cast<const float4*>(kb + (size_t)c * kN + min(k0 + x4, kN - 4));
    }
    // Stage q-tile pre-scaled: 128 c x 16 float4 (16 iters).
#pragma unroll
    for (int i = t; i < kC * 16; i += 128) {
        const int c  = i >> 4;
        const int x4 = (i & 15) << 2;
        float4 qv = *reinterpret_cast<const float4*>(qb + (size_t)c * kN + min(q0 + x4, kN - 4));
        qv.x *= kInvT; qv.y *= kInvT; qv.z *= kInvT; qv.w *= kInvT;
        *reinterpret_cast<float4*>(&qs[c][x4]) = qv;
    }
    __syncthreads();

    const int qx = (t & 15) << 2;  // 16 q-groups (b128, 2-way = free)
    const int kx = (t >> 4) << 2;  // 8 k-groups (b128, 16-lane broadcast)

    float acc[4][4];
#pragma unroll
    for (int i = 0; i < 4; ++i)
#pragma unroll
        for (int j = 0; j < 4; ++j) acc[i][j] = 0.0f;

#pragma unroll 4
    for (int c = 0; c < kC; ++c) {
        const float4 kv = *reinterpret_cast<const float4*>(&ks[c][kx]);
        const float4 qv = *reinterpret_cast<const float4*>(&qs[c][qx]);
        const float kf[4] = {kv.x, kv.y, kv.z, kv.w};
        const float qf[4] = {qv.x, qv.y, qv.z, qv.w};
#pragma unroll
        for (int i = 0; i < 4; ++i)
#pragma unroll
            for (int j = 0; j < 4; ++j)
                acc[i][j] += fabsf(qf[j] - kf[i]);
    }

    // exp (no max subtraction needed: arg in [~0.3, ~2.5])
#pragma unroll
    for (int i = 0; i < 4; ++i)
#pragma unroll
        for (int j = 0; j < 4; ++j)
            acc[i][j] = __expf(acc[i][j] * kInvC);

    const int qcol = q0 + qx;
    const bool qvalid = qcol < kN;  // 784%4==0: float4 all-valid or all-out
    if (qvalid) {
#pragma unroll
        for (int i = 0; i < 4; ++i) {
            const int krow = k0 + kx + i;
            if (krow < kN) {
                *reinterpret_cast<float4*>(&attn[((size_t)b * kN + krow) * kN + qcol]) =
                    make_float4(acc[i][0], acc[i][1], acc[i][2], acc[i][3]);
            }
        }
    }

    // Per-row partial sums over this tile's 64 q: shfl-reduce across the 16 q-lanes.
    float psum[4];
#pragma unroll
    for (int i = 0; i < 4; ++i)
        psum[i] = qvalid ? (acc[i][0] + acc[i][1] + acc[i][2] + acc[i][3]) : 0.0f;
#pragma unroll
    for (int m = 1; m < 16; m <<= 1) {
#pragma unroll
        for (int i = 0; i < 4; ++i)
            psum[i] += __shfl_xor(psum[i], m, 64);
    }
    if ((t & 15) == 0) {
        const int base = ((b * DNKT + kt) * DNQT + qt) * DK + kx;
#pragma unroll
        for (int i = 0; i < 4; ++i)
            lp[base + i] = psum[i];  // rows >= kN store garbage, never read
    }
}

// ========== Kernel 2: partial[qs][b,c,k] = sum_{q slice} v[b,c,q] * p[b,k,q] ==========
// Unchanged proven structure; reads UNNORMALIZED p (scale folded into finalize).
template <bool ATOMIC>
__global__ __launch_bounds__(256) void bmm_stage1(const float* __restrict__ vg,
                                                  const float* __restrict__ attn,
                                                  float* __restrict__ P) {
    int bid = blockIdx.x;
    const int qs = bid % QSP;   bid /= QSP;
    const int kt = bid % NKT2;  bid /= NKT2;
    const int ct = bid & 1;     bid >>= 1;
    const int b  = bid;
    const int k0 = kt * BKT;
    const int c0 = ct * 64;
    const int qb0 = qs * QPB;
    const int t  = threadIdx.x;

    __shared__ float vT[QCH][BSTR];
    __shared__ float aT[QCH][BSTR];

    const int cc = t >> 2;
    const int j1 = t & 3;
    const int j2 = j1 + 4;
    const int c0l = (t >> 4) << 2;  // c: wave-broadcast reads
    const int k0l = (t & 15) << 2;  // k: lane-fast (coalesced stores)

    float acc[4][4];
#pragma unroll
    for (int i = 0; i < 4; ++i)
#pragma unroll
        for (int j = 0; j < 4; ++j) acc[i][j] = 0.0f;

    const float* vb = vg + ((size_t)b * kC + c0) * kN;
    const float* ab = attn + (size_t)b * kN * kN;
    const int krow_st = min(k0 + cc, kN - 1);

    for (int qc = 0; qc < QPB; qc += QCH) {
        const int q0 = qb0 + qc;
        const float4 vv1 = *reinterpret_cast<const float4*>(vb + (size_t)cc * kN + q0 + 4 * j1);
        const float4 av1 = *reinterpret_cast<const float4*>(ab + (size_t)krow_st * kN + q0 + 4 * j1);
        float4 vv2, av2;
        const bool has2 = (j2 < 7);
        if (has2) {
            vv2 = *reinterpret_cast<const float4*>(vb + (size_t)cc * kN + q0 + 4 * j2);
            av2 = *reinterpret_cast<const float4*>(ab + (size_t)krow_st * kN + q0 + 4 * j2);
        }
        __syncthreads();
        {
            const int r1 = 4 * j1;
            vT[r1 + 0][cc] = vv1.x; vT[r1 + 1][cc] = vv1.y;
            vT[r1 + 2][cc] = vv1.z; vT[r1 + 3][cc] = vv1.w;
            aT[r1 + 0][cc] = av1.x; aT[r1 + 1][cc] = av1.y;
            aT[r1 + 2][cc] = av1.z; aT[r1 + 3][cc] = av1.w;
            if (has2) {
                const int r2 = 4 * j2;
                vT[r2 + 0][cc] = vv2.x; vT[r2 + 1][cc] = vv2.y;
                vT[r2 + 2][cc] = vv2.z; vT[r2 + 3][cc] = vv2.w;
                aT[r2 + 0][cc] = av2.x; aT[r2 + 1][cc] = av2.y;
                aT[r2 + 2][cc] = av2.z; aT[r2 + 3][cc] = av2.w;
            }
        }
        __syncthreads();

#pragma unroll
        for (int qq = 0; qq < QCH; ++qq) {
            const float4 vf4 = *reinterpret_cast<const float4*>(&vT[qq][c0l]);
            const float4 af4 = *reinterpret_cast<const float4*>(&aT[qq][k0l]);
            const float vf[4] = {vf4.x, vf4.y, vf4.z, vf4.w};
            const float af[4] = {af4.x, af4.y, af4.z, af4.w};
#pragma unroll
            for (int i = 0; i < 4; ++i)
#pragma unroll
                for (int j = 0; j < 4; ++j) acc[i][j] += vf[i] * af[j];
        }
    }

    if (ATOMIC) {
#pragma unroll
        for (int i = 0; i < 4; ++i) {
            const int c = c0 + c0l + i;
#pragma unroll
            for (int j = 0; j < 4; ++j) {
                const int krow = k0 + k0l + j;
                if (krow < kN)
                    atomicAdd(&P[((size_t)b * kC + c) * kN + krow], acc[i][j]);
            }
        }
    } else if (k0 + k0l < kN) {
#pragma unroll
        for (int i = 0; i < 4; ++i) {
            const int c = c0 + c0l + i;
            *reinterpret_cast<float4*>(
                P + (((size_t)qs * kB + b) * kC + c) * kN + k0 + k0l) =
                make_float4(acc[i][0], acc[i][1], acc[i][2], acc[i][3]);
        }
    }
}

// ========== Kernel 3: finalize — normalize attn (p/l) and out = (sum_qs P)/l ==========
// Blocks [0,NNORM): wave-per-row attn normalize. Blocks [NNORM, NNORM+NOUTB): out.
__global__ __launch_bounds__(256) void finalize(float* __restrict__ attn,
                                                const float* __restrict__ P,
                                                const float* __restrict__ lp,
                                                float* __restrict__ out) {
    const int t = threadIdx.x;
    if ((int)blockIdx.x < NNORM) {
        const int wid = t >> 6, lane = t & 63;
        const int r = (int)blockIdx.x * 4 + wid;  // < 1568
        const int b = r / kN, k = r % kN;
        const int kt = k >> 5, kk = k & 31;
        const int base = ((b * DNKT + kt) * DNQT) * DK + kk;
        float l = 0.0f;
#pragma unroll
        for (int qt = 0; qt < DNQT; ++qt) l += lp[base + qt * DK];
        const float inv = 1.0f / l;

        float4* A4 = reinterpret_cast<float4*>(attn + (size_t)r * kN);
        float4 x0 = A4[lane], x1 = A4[lane + 64], x2 = A4[lane + 128];
        x0.x *= inv; x0.y *= inv; x0.z *= inv; x0.w *= inv;
        x1.x *= inv; x1.y *= inv; x1.z *= inv; x1.w *= inv;
        x2.x *= inv; x2.y *= inv; x2.z *= inv; x2.w *= inv;
        A4[lane] = x0; A4[lane + 64] = x1; A4[lane + 128] = x2;
        if (lane < 4) {  // 196 = 3*64 + 4
            float4 x3 = A4[lane + 192];
            x3.x *= inv; x3.y *= inv; x3.z *= inv; x3.w *= inv;
            A4[lane + 192] = x3;
        }
    } else {
        const int idx = ((int)blockIdx.x - NNORM) * 256 + t;  // < 50176
        const int e0 = idx * 4;
        const int k4 = e0 % kN;            // multiple of 4 (784%4==0)
        const int row = e0 / kN;           // b*128 + c
        const int b = row >> 7;
        const int kt = k4 >> 5, kk = k4 & 31;  // kk <= 28, float4 stays in-tile
        const int base = ((b * DNKT + kt) * DNQT) * DK + kk;
        float4 l4 = make_float4(0.f, 0.f, 0.f, 0.f);
#pragma unroll
        for (int qt = 0; qt < DNQT; ++qt) {
            const float4 v = *reinterpret_cast<const float4*>(&lp[base + qt * DK]);
            l4.x += v.x; l4.y += v.y; l4.z += v.z; l4.w += v.w;
        }
        const float4* p = reinterpret_cast<const float4*>(P) + idx;
        float4 s = p[0];
#pragma unroll
        for (int qs = 1; qs < QSP; ++qs) {
            const float4 v = p[(size_t)qs * (kOutElems / 4)];
            s.x += v.x; s.y += v.y; s.z += v.z; s.w += v.w;
        }
        s.x /= l4.x; s.y /= l4.y; s.z /= l4.z; s.w /= l4.w;
        reinterpret_cast<float4*>(out)[idx] = s;
    }
}

// ======================= Fallback path (ws too small; never expected) =======================
__global__ __launch_bounds__(256) void dist_fb(const float* __restrict__ qg,
                                               const float* __restrict__ kg,
                                               float* __restrict__ D0) {
    int bid = blockIdx.x;
    const int qt = bid % DNQT; bid /= DNQT;
    const int kt = bid % DNKT; bid /= DNKT;
    const int b  = bid;
    const int k0 = kt * DK, q0 = qt * DQ;
    const int t = threadIdx.x;  // 128
    __shared__ float ks[kC][KSTR];
    __shared__ float qs[kC][QSTR];
    const float* kb = kg + (size_t)b * kC * kN;
    const float* qb = qg + (size_t)b * kC * kN;
    for (int i = t; i < kC * 8; i += 128) {
        const int c = i >> 3, x4 = (i & 7) << 2;
        *reinterpret_cast<float4*>(&ks[c][x4]) =
            *reinterpret_cast<const float4*>(kb + (size_t)c * kN + min(k0 + x4, kN - 4));
    }
    for (int i = t; i < kC * 16; i += 128) {
        const int c = i >> 4, x4 = (i & 15) << 2;
        float4 qv = *reinterpret_cast<const float4*>(qb + (size_t)c * kN + min(q0 + x4, kN - 4));
        qv.x *= kInvT; qv.y *= kInvT; qv.z *= kInvT; qv.w *= kInvT;
        *reinterpret_cast<float4*>(&qs[c][x4]) = qv;
    }
    __syncthreads();
    const int qx = (t & 15) << 2, kx = (t >> 4) << 2;
    float acc[4][4];
    for (int i = 0; i < 4; ++i)
        for (int j = 0; j < 4; ++j) acc[i][j] = 0.0f;
    for (int c = 0; c < kC; ++c) {
        const float4 kv = *reinterpret_cast<const float4*>(&ks[c][kx]);
        const float4 qv = *reinterpret_cast<const float4*>(&qs[c][qx]);
        const float kf[4] = {kv.x, kv.y, kv.z, kv.w};
        const float qf[4] = {qv.x, qv.y, qv.z, qv.w};
        for (int i = 0; i < 4; ++i)
            for (int j = 0; j < 4; ++j) acc[i][j] += fabsf(qf[j] - kf[i]);
    }
    const int qcol = q0 + qx;
    if (qcol < kN)
        for (int i = 0; i < 4; ++i) {
            const int krow = k0 + kx + i;
            if (krow < kN) {
                *reinterpret_cast<float4*>(&D0[((size_t)b * kN + krow) * kN + qcol]) =
                    make_float4(acc[i][0], acc[i][1], acc[i][2], acc[i][3]);
            }
        }
}

__global__ __launch_bounds__(256) void softmax_fb(float* __restrict__ A) {
    float4* A4 = reinterpret_cast<float4*>(A + (size_t)blockIdx.x * kN);
    const int t = threadIdx.x, lane = t & 63, wid = t >> 6;
    const bool act = t < (kN / 4);
    __shared__ float xred[4];
    float4 x = make_float4(-1e30f, -1e30f, -1e30f, -1e30f);
    if (act) x = A4[t];
    float m = fmaxf(fmaxf(x.x, x.y), fmaxf(x.z, x.w));
    m = wave_max(m);
    if (lane == 0) xred[wid] = m;
    __syncthreads();
    m = fmaxf(fmaxf(xred[0], xred[1]), fmaxf(xred[2], xred[3]));
    __syncthreads();
    float4 p;
    p.x = __expf((x.x - m) * kInvC); p.y = __expf((x.y - m) * kInvC);
    p.z = __expf((x.z - m) * kInvC); p.w = __expf((x.w - m) * kInvC);
    float ls = p.x + p.y + p.z + p.w;
    ls = wave_sum(ls);
    if (lane == 0) xred[wid] = ls;
    __syncthreads();
    const float inv = 1.0f / (xred[0] + xred[1] + xred[2] + xred[3]);
    if (act) { p.x *= inv; p.y *= inv; p.z *= inv; p.w *= inv; A4[t] = p; }
}

extern "C" void kernel_launch(void* const* d_in, const int* in_sizes, int n_in,
                              void* d_out, int out_size, void* d_ws, size_t ws_size,
                              hipStream_t stream) {
    const float* q = (const float*)d_in[0];
    const float* k = (const float*)d_in[1];
    const float* v = (const float*)d_in[2];

    float* out  = (float*)d_out;               // [B, C, N]
    float* attn = out + kOutElems;             // [B, N, N]
    float* P    = (float*)d_ws;                // [QSP][B, C, N] bmm partials
    float* lp   = P + (size_t)QSP * kOutElems; // [B*25*13][32] row-sum partials

    const size_t need = ((size_t)QSP * kOutElems + (size_t)NDISTE * DK) * sizeof(float);

    if (ws_size >= need) {
        dist_exp<<<NDISTE, 128, 0, stream>>>(q, k, attn, lp);
        bmm_stage1<false><<<NBMM, 256, 0, stream>>>(v, attn, P);
        finalize<<<NNORM + NOUTB, 256, 0, stream>>>(attn, P, lp, out);
    } else {
        // Fallback without workspace: raw dist -> max-softmax -> atomic bmm.
        hipMemsetAsync(out, 0, kOutElems * sizeof(float), stream);
        dist_fb<<<NDISTE, 128, 0, stream>>>(q, k, attn);
        softmax_fb<<<NROWS, 256, 0, stream>>>(attn);
        bmm_stage1<true><<<NBMM, 256, 0, stream>>>(v, attn, out);
    }
}